// Round 1
// baseline (528.842 us; speedup 1.0000x reference)
//
#include <hip/hip_runtime.h>
#include <hip/hip_bf16.h>
#include <stdint.h>

typedef __attribute__((ext_vector_type(4))) float f32x4;
typedef __attribute__((ext_vector_type(8))) short short8;
typedef __attribute__((ext_vector_type(8))) unsigned short u16x8;
typedef __attribute__((ext_vector_type(4))) unsigned short u16x4;

__device__ __forceinline__ unsigned short f2bf(float f) {
  unsigned int u = __float_as_uint(f);
  u += 0x7fffu + ((u >> 16) & 1u);
  return (unsigned short)(u >> 16);
}
__device__ __forceinline__ float bf2f(unsigned short h) {
  return __uint_as_float(((unsigned int)h) << 16);
}

// ---------------- kernel 0: W (512x512 f32) -> WT (bf16, transposed) ----------------
__global__ __launch_bounds__(256) void k_twp(const float* __restrict__ W,
                                             unsigned short* __restrict__ WT) {
  __shared__ float tile[64][65];
  int tid = threadIdx.x;
  int c = tid & 63, r0 = tid >> 6;
  int kb = blockIdx.x * 64, nb = blockIdx.y * 64;
#pragma unroll
  for (int rr = 0; rr < 16; ++rr) {
    int r = rr * 4 + r0;
    tile[r][c] = W[(size_t)(kb + r) * 512 + nb + c];
  }
  __syncthreads();
#pragma unroll
  for (int rr = 0; rr < 16; ++rr) {
    int r = rr * 4 + r0;
    WT[(size_t)(nb + r) * 512 + kb + c] = f2bf(tile[c][r]);
  }
}

// ---------------- kernel 1: Wh^T = (h @ W)^T, written as WhT[b][n][j] bf16 ----------------
// A = h rows (fp32, converted to bf16 during staging), B = WT rows (bf16).
// 128x128 tile, BK=64, 4 waves (2x2), 16x16x32 MFMA, XOR-swizzled LDS.
__global__ __launch_bounds__(256) void k_gemm(const float* __restrict__ xa,
                                              const float* __restrict__ xv,
                                              const unsigned short* __restrict__ WT,
                                              unsigned short* __restrict__ WhT) {
  __shared__ __align__(16) unsigned short Al[128 * 64];
  __shared__ __align__(16) unsigned short Bl[128 * 64];
  int tid = threadIdx.x;
  int nblk = blockIdx.x;   // 0..3
  int mblk = blockIdx.y;   // 0..255
  int R0g = mblk * 128;
  int b = R0g >> 11;
  int iloc = R0g & 2047;
  const float* Abase = (iloc < 1024)
      ? (xa + ((size_t)b * 1024 + iloc) * 512)
      : (xv + ((size_t)b * 1024 + (iloc - 1024)) * 512);
  int n0 = nblk * 128;

  int lane = tid & 63;
  int wid = tid >> 6;
  int wr = wid >> 1, wc = wid & 1;

  f32x4 acc[4][4];
#pragma unroll
  for (int i = 0; i < 4; ++i) {
#pragma unroll
    for (int j = 0; j < 4; ++j) acc[i][j] = (f32x4){0.f, 0.f, 0.f, 0.f};
  }

  for (int kt = 0; kt < 8; ++kt) {
    int k0 = kt * 64;
    __syncthreads();
    // stage A: fp32 -> bf16, 128 rows x 64 k. 2048 source granules of 16B.
#pragma unroll
    for (int pass = 0; pass < 8; ++pass) {
      int gl = pass * 256 + tid;
      int row = gl >> 4;   // 16 granules (4 floats) per 256B source row
      int gg = gl & 15;
      float4 v = *((const float4*)(Abase + (size_t)row * 512 + k0) + gg);
      u16x4 pk;
      pk.x = f2bf(v.x); pk.y = f2bf(v.y); pk.z = f2bf(v.z); pk.w = f2bf(v.w);
      int boff = (gg * 8) ^ ((row & 7) << 4);
      *(u16x4*)((char*)Al + row * 128 + boff) = pk;
    }
    // stage B: bf16 passthrough, 128 rows x 64 k.
#pragma unroll
    for (int pass = 0; pass < 4; ++pass) {
      int gl = pass * 256 + tid;
      int row = gl >> 3;   // 8 granules (16B) per 128B row
      int g = gl & 7;
      u16x8 v = *(const u16x8*)(WT + (size_t)(n0 + row) * 512 + k0 + g * 8);
      int boff = (g * 16) ^ ((row & 7) << 4);
      *(u16x8*)((char*)Bl + row * 128 + boff) = v;
    }
    __syncthreads();
#pragma unroll
    for (int kc = 0; kc < 2; ++kc) {
      short8 af[4], bf[4];
#pragma unroll
      for (int mf = 0; mf < 4; ++mf) {
        int row = wr * 64 + mf * 16 + (lane & 15);
        int boff = ((kc * 4 + (lane >> 4)) * 16) ^ ((row & 7) << 4);
        af[mf] = *(const short8*)((const char*)Al + row * 128 + boff);
      }
#pragma unroll
      for (int nf = 0; nf < 4; ++nf) {
        int row = wc * 64 + nf * 16 + (lane & 15);
        int boff = ((kc * 4 + (lane >> 4)) * 16) ^ ((row & 7) << 4);
        bf[nf] = *(const short8*)((const char*)Bl + row * 128 + boff);
      }
#pragma unroll
      for (int mf = 0; mf < 4; ++mf) {
#pragma unroll
        for (int nf = 0; nf < 4; ++nf)
          acc[mf][nf] = __builtin_amdgcn_mfma_f32_16x16x32_bf16(af[mf], bf[nf], acc[mf][nf], 0, 0, 0);
      }
    }
  }
  // epilogue: C row = j (A row), col = n. Write WhT[b][n][j], 4 consecutive j per lane.
#pragma unroll
  for (int mf = 0; mf < 4; ++mf) {
    int jrow = iloc + wr * 64 + mf * 16 + ((lane >> 4) << 2);
#pragma unroll
    for (int nf = 0; nf < 4; ++nf) {
      int n = n0 + wc * 64 + nf * 16 + (lane & 15);
      u16x4 pk;
#pragma unroll
      for (int e = 0; e < 4; ++e) pk[e] = f2bf(acc[mf][nf][e]);
      *(u16x4*)(WhT + ((size_t)b * 512 + n) * 2048 + jrow) = pk;
    }
  }
}

// ---------------- kernel 2: s1/s2 = WhT^T . a1/a2 ; F1=exp(s2), F2=exp(0.1 s2) ----------------
__global__ __launch_bounds__(256) void k_s(const unsigned short* __restrict__ WhT,
                                           const float* __restrict__ a,
                                           float* __restrict__ s1, float* __restrict__ s2,
                                           float* __restrict__ f1, float* __restrict__ f2) {
  __shared__ float a1l[512], a2l[512];
  __shared__ float p1[256], p2[256];
  int tid = threadIdx.x;
  int b = blockIdx.y;
#pragma unroll
  for (int i = 0; i < 2; ++i) {
    a1l[tid + i * 256] = a[tid + i * 256];
    a2l[tid + i * 256] = a[512 + tid + i * 256];
  }
  __syncthreads();
  int j = blockIdx.x * 128 + (tid & 127);
  int nh = tid >> 7;
  const unsigned short* base = WhT + ((size_t)b * 512 + nh * 256) * 2048 + j;
  float c1 = 0.f, c2 = 0.f;
#pragma unroll 8
  for (int n = 0; n < 256; ++n) {
    float w = bf2f(base[(size_t)n * 2048]);
    c1 += w * a1l[nh * 256 + n];
    c2 += w * a2l[nh * 256 + n];
  }
  p1[tid] = c1; p2[tid] = c2;
  __syncthreads();
  if (tid < 128) {
    float v1 = p1[tid] + p1[tid + 128];
    float v2 = p2[tid] + p2[tid + 128];
    size_t o = (size_t)b * 2048 + j;
    s1[o] = v1; s2[o] = v2;
    f1[o] = __expf(v2);
    f2[o] = __expf(0.1f * v2);
  }
}

// ---------------- kernel 3: fused masked-softmax attention + PV + elu ----------------
// 1 WG / CU (grid 256). 512 thr (8 waves, 2 row x 4 col). 128-row block, 64-j tiles.
__global__ __launch_bounds__(512) void k_attn(const int* __restrict__ adj,
                                              const unsigned short* __restrict__ WhT,
                                              const float* __restrict__ s1g,
                                              const float* __restrict__ s2g,
                                              const float* __restrict__ f1g,
                                              const float* __restrict__ f2g,
                                              float* __restrict__ out) {
  __shared__ __align__(16) unsigned short Pl[128 * 64];
  __shared__ __align__(16) unsigned short Bl[512 * 64];
  __shared__ float s2l[2048];
  __shared__ float f1l[2048];
  __shared__ float f2l[2048];
  __shared__ float zl[128];
  __shared__ float red[8];
  int tid = threadIdx.x;
  // XCD-aware swizzle: XCD k owns batches {2k, 2k+1} -> its 4MB L2 holds their WhT.
  int bx = blockIdx.x;
  int q = bx >> 3, xcd = bx & 7;
  int b = xcd * 2 + (q & 1);
  int rb = q >> 1;
  int R0 = rb * 128;

  int lane = tid & 63;
  int wid = tid >> 6;

  // init: stage s2/F1/F2 rows of this batch; block-reduce gmax = max(s2)
  float lm = -1e30f;
#pragma unroll
  for (int i = 0; i < 4; ++i) {
    int idx = i * 512 + tid;
    float v = s2g[(size_t)b * 2048 + idx];
    s2l[idx] = v;
    f1l[idx] = f1g[(size_t)b * 2048 + idx];
    f2l[idx] = f2g[(size_t)b * 2048 + idx];
    lm = fmaxf(lm, v);
  }
#pragma unroll
  for (int s = 1; s < 64; s <<= 1) lm = fmaxf(lm, __shfl_xor(lm, s));
  if (lane == 0) red[wid] = lm;
  __syncthreads();
  float gmax = red[0];
#pragma unroll
  for (int i = 1; i < 8; ++i) gmax = fmaxf(gmax, red[i]);

  // per-thread row constants for the staging role (4 threads per row)
  int r = tid >> 2;
  int qc = tid & 3;
  float s1r = s1g[(size_t)b * 2048 + R0 + r];
  float t0 = s1r + gmax;
  float M = (t0 > 0.f) ? t0 : 0.1f * t0;       // leakyrelu upper bound -> softmax shift
  float E1 = __expf(s1r - M);
  float E2 = __expf(0.1f * s1r - M);
  float zacc = 0.f;

  f32x4 acc[4][8];
#pragma unroll
  for (int i = 0; i < 4; ++i) {
#pragma unroll
    for (int j = 0; j < 8; ++j) acc[i][j] = (f32x4){0.f, 0.f, 0.f, 0.f};
  }

  int wr2 = wid >> 2, wc = wid & 3;
  const int* adjbase = adj + ((size_t)b * 2048 + R0 + r) * 2048 + qc * 16;
  const unsigned short* whbase = WhT + (size_t)b * 512 * 2048;

  for (int jt = 0; jt < 32; ++jt) {
    int j0 = jt * 64;
    __syncthreads();
    // ---- stage P: p = adj ? E'(sign)*F'(sign) : 0 ; no transcendentals ----
    {
      int4 av[4];
#pragma unroll
      for (int u = 0; u < 4; ++u) av[u] = *(const int4*)(adjbase + j0 + u * 4);
      const int* avs = (const int*)av;
#pragma unroll
      for (int half = 0; half < 2; ++half) {
        u16x8 pk;
#pragma unroll
        for (int c = 0; c < 8; ++c) {
          int cc = half * 8 + c;
          int jl = j0 + qc * 16 + cc;
          float t = s1r + s2l[jl];
          bool pos = t > 0.f;
          float Ev = pos ? E1 : E2;
          float Fv = pos ? f1l[jl] : f2l[jl];
          float p = (avs[cc] > 0) ? Ev * Fv : 0.f;
          unsigned short pb = f2bf(p);
          zacc += bf2f(pb);          // denominator from the *rounded* p (consistency)
          pk[c] = pb;
        }
        int boff = (qc * 32 + half * 16) ^ ((r & 7) << 4);
        *(u16x8*)((char*)Pl + r * 128 + boff) = pk;
      }
    }
    // ---- stage B: WhT[n][j0..j0+64], 512 rows of 128B ----
#pragma unroll
    for (int pass = 0; pass < 8; ++pass) {
      int n = pass * 64 + (tid >> 3);
      int g = tid & 7;
      u16x8 v = *(const u16x8*)(whbase + (size_t)n * 2048 + j0 + g * 8);
      int boff = (g * 16) ^ ((n & 7) << 4);
      *(u16x8*)((char*)Bl + n * 128 + boff) = v;
    }
    __syncthreads();
    // ---- MFMA: acc += P(128x64) @ Wh(64x512), per wave 64x128 ----
#pragma unroll
    for (int kc = 0; kc < 2; ++kc) {
      short8 af[4]; short8 bfr[8];
#pragma unroll
      for (int mf = 0; mf < 4; ++mf) {
        int row = wr2 * 64 + mf * 16 + (lane & 15);
        int boff = ((kc * 4 + (lane >> 4)) * 16) ^ ((row & 7) << 4);
        af[mf] = *(const short8*)((const char*)Pl + row * 128 + boff);
      }
#pragma unroll
      for (int nf = 0; nf < 8; ++nf) {
        int n = wc * 128 + nf * 16 + (lane & 15);
        int boff = ((kc * 4 + (lane >> 4)) * 16) ^ ((n & 7) << 4);
        bfr[nf] = *(const short8*)((const char*)Bl + n * 128 + boff);
      }
#pragma unroll
      for (int mf = 0; mf < 4; ++mf) {
#pragma unroll
        for (int nf = 0; nf < 8; ++nf)
          acc[mf][nf] = __builtin_amdgcn_mfma_f32_16x16x32_bf16(af[mf], bfr[nf], acc[mf][nf], 0, 0, 0);
      }
    }
  }
  // ---- z reduction: 4 staging threads per row are adjacent lanes ----
  zacc += __shfl_xor(zacc, 1);
  zacc += __shfl_xor(zacc, 2);
  if (qc == 0) zl[r] = zacc;
  __syncthreads();

  // ---- epilogue: h' = elu(acc / z), split into the two outputs ----
  float* obase;
  if (R0 < 1024) obase = out + ((size_t)b * 1024 + R0) * 512;
  else obase = out + (size_t)8388608 + ((size_t)b * 1024 + (R0 - 1024)) * 512;
#pragma unroll
  for (int mf = 0; mf < 4; ++mf) {
    int row0 = wr2 * 64 + mf * 16 + ((lane >> 4) << 2);
    float zi[4];
#pragma unroll
    for (int e = 0; e < 4; ++e) zi[e] = 1.f / zl[row0 + e];
#pragma unroll
    for (int nf = 0; nf < 8; ++nf) {
      int n = wc * 128 + nf * 16 + (lane & 15);
#pragma unroll
      for (int e = 0; e < 4; ++e) {
        float v = acc[mf][nf][e] * zi[e];
        v = (v > 0.f) ? v : (__expf(v) - 1.f);
        obase[(size_t)(row0 + e) * 512 + n] = v;
      }
    }
  }
}

extern "C" void kernel_launch(void* const* d_in, const int* in_sizes, int n_in,
                              void* d_out, int out_size, void* d_ws, size_t ws_size,
                              hipStream_t stream) {
  (void)in_sizes; (void)n_in; (void)out_size; (void)ws_size;
  const float* x_a = (const float*)d_in[0];
  const float* x_v = (const float*)d_in[1];
  const int*   adj = (const int*)d_in[2];
  const float* W   = (const float*)d_in[3];
  const float* a   = (const float*)d_in[4];
  float* out = (float*)d_out;

  char* ws = (char*)d_ws;
  unsigned short* WT  = (unsigned short*)ws;                       // 512 KB
  unsigned short* WhT = (unsigned short*)(ws + (1u << 19));        // 32 MB
  float* s1 = (float*)(ws + (1u << 19) + (1u << 25));              // 128 KB each
  float* s2 = s1 + 32768;
  float* f1 = s2 + 32768;
  float* f2 = f1 + 32768;

  hipLaunchKernelGGL(k_twp,  dim3(8, 8),    dim3(256), 0, stream, W, WT);
  hipLaunchKernelGGL(k_gemm, dim3(4, 256),  dim3(256), 0, stream, x_a, x_v, WT, WhT);
  hipLaunchKernelGGL(k_s,    dim3(16, 16),  dim3(256), 0, stream, WhT, a, s1, s2, f1, f2);
  hipLaunchKernelGGL(k_attn, dim3(256),     dim3(512), 0, stream, adj, WhT, s1, s2, f1, f2, out);
}

// Round 2
// 498.327 us; speedup vs baseline: 1.0612x; 1.0612x over previous
//
#include <hip/hip_runtime.h>
#include <hip/hip_bf16.h>
#include <stdint.h>

typedef __attribute__((ext_vector_type(4))) float f32x4;
typedef __attribute__((ext_vector_type(8))) short short8;
typedef __attribute__((ext_vector_type(8))) unsigned short u16x8;
typedef __attribute__((ext_vector_type(4))) unsigned short u16x4;

typedef __attribute__((address_space(1))) const unsigned int as1_u32;
typedef __attribute__((address_space(3))) unsigned int as3_u32;
#define GLD16(src, dst) __builtin_amdgcn_global_load_lds((as1_u32*)(src), (as3_u32*)(dst), 16, 0, 0)

__device__ __forceinline__ unsigned short f2bf(float f) {
  unsigned int u = __float_as_uint(f);
  u += 0x7fffu + ((u >> 16) & 1u);
  return (unsigned short)(u >> 16);
}
__device__ __forceinline__ float bf2f(unsigned short h) {
  return __uint_as_float(((unsigned int)h) << 16);
}

// ---------------- kernel 0: W (512x512 f32) -> WT (bf16, transposed) ----------------
__global__ __launch_bounds__(256) void k_twp(const float* __restrict__ W,
                                             unsigned short* __restrict__ WT) {
  __shared__ float tile[64][65];
  int tid = threadIdx.x;
  int c = tid & 63, r0 = tid >> 6;
  int kb = blockIdx.x * 64, nb = blockIdx.y * 64;
#pragma unroll
  for (int rr = 0; rr < 16; ++rr) {
    int r = rr * 4 + r0;
    tile[r][c] = W[(size_t)(kb + r) * 512 + nb + c];
  }
  __syncthreads();
#pragma unroll
  for (int rr = 0; rr < 16; ++rr) {
    int r = rr * 4 + r0;
    WT[(size_t)(nb + r) * 512 + kb + c] = f2bf(tile[c][r]);
  }
}

// ---------------- kernel 1: Wh^T, WG tile 64 rows x 512 n (x read exactly once) ----------------
// 4 waves, each 64x128. A: fp32->bf16 reg-staged; B(WT): global_load_lds w/ pre-swizzled src.
__global__ __launch_bounds__(256, 2) void k_gemm(const float* __restrict__ xa,
                                                 const float* __restrict__ xv,
                                                 const unsigned short* __restrict__ WT,
                                                 unsigned short* __restrict__ WhT) {
  __shared__ __align__(16) unsigned short Al[64 * 64];    // 8KB, row 128B
  __shared__ __align__(16) unsigned short Bl[512 * 64];   // 64KB, row 128B
  int tid = threadIdx.x;
  int rblk = blockIdx.x;
  int R0g = rblk * 64;
  int b = R0g >> 11;
  int iloc = R0g & 2047;
  const float* Abase = (iloc < 1024)
      ? (xa + ((size_t)b * 1024 + iloc) * 512)
      : (xv + ((size_t)b * 1024 + (iloc - 1024)) * 512);

  int lane = tid & 63;
  int wid = tid >> 6;
  int wc = wid;              // n-slice of 128 per wave

  f32x4 acc[4][8];
#pragma unroll
  for (int i = 0; i < 4; ++i)
#pragma unroll
    for (int j = 0; j < 8; ++j) acc[i][j] = (f32x4){0.f, 0.f, 0.f, 0.f};

  for (int kt = 0; kt < 8; ++kt) {
    int k0 = kt * 64;
    __syncthreads();
    // stage A: 64 rows x 64 k, fp32 -> bf16, swizzled ds_write
#pragma unroll
    for (int pass = 0; pass < 4; ++pass) {
      int row = pass * 16 + (tid >> 4);
      int gg = tid & 15;
      float4 v = *((const float4*)(Abase + (size_t)row * 512 + k0) + gg);
      u16x4 pk;
      pk.x = f2bf(v.x); pk.y = f2bf(v.y); pk.z = f2bf(v.z); pk.w = f2bf(v.w);
      *(u16x4*)((char*)Al + row * 128 + ((gg * 8) ^ ((row & 7) << 4))) = pk;
    }
    // stage B: all 512 WT rows x 64 k via global_load_lds, source pre-swizzled
#pragma unroll
    for (int pass = 0; pass < 16; ++pass) {
      int n = pass * 32 + (tid >> 3);
      int g = tid & 7;
      const unsigned short* src = WT + (size_t)n * 512 + k0 + ((g ^ (n & 7)) << 3);
      unsigned short* dst = Bl + pass * 2048 + wid * 512;
      GLD16(src, dst);
    }
    __syncthreads();
#pragma unroll
    for (int kc = 0; kc < 2; ++kc) {
      int u = kc * 4 + (lane >> 4);
      short8 af[4];
#pragma unroll
      for (int mf = 0; mf < 4; ++mf) {
        int row = mf * 16 + (lane & 15);
        af[mf] = *(const short8*)((const char*)Al + row * 128 + (((u ^ (row & 7)) & 7) << 4));
      }
#pragma unroll
      for (int nf = 0; nf < 8; ++nf) {
        int n = wc * 128 + nf * 16 + (lane & 15);
        short8 bv = *(const short8*)((const char*)Bl + n * 128 + (((u ^ (n & 7)) & 7) << 4));
#pragma unroll
        for (int mf = 0; mf < 4; ++mf)
          acc[mf][nf] = __builtin_amdgcn_mfma_f32_16x16x32_bf16(af[mf], bv, acc[mf][nf], 0, 0, 0);
      }
    }
  }
  // epilogue: write WhT[b][n][jrow]
#pragma unroll
  for (int mf = 0; mf < 4; ++mf) {
    int jrow = iloc + mf * 16 + ((lane >> 4) << 2);
#pragma unroll
    for (int nf = 0; nf < 8; ++nf) {
      int n = wc * 128 + nf * 16 + (lane & 15);
      u16x4 pk;
#pragma unroll
      for (int e = 0; e < 4; ++e) pk[e] = f2bf(acc[mf][nf][e]);
      *(u16x4*)(WhT + ((size_t)b * 512 + n) * 2048 + jrow) = pk;
    }
  }
}

// ---------------- kernel 2: s1/s2 = WhT^T . a1/a2 ; F1=exp(s2), F2=exp(0.1 s2) ----------------
// vectorized: 8 consecutive j per thread, u16x8 loads
__global__ __launch_bounds__(256) void k_s(const unsigned short* __restrict__ WhT,
                                           const float* __restrict__ a,
                                           float* __restrict__ s1, float* __restrict__ s2,
                                           float* __restrict__ f1, float* __restrict__ f2) {
  __shared__ float a1l[512], a2l[512];
  __shared__ float S1p[8][256], S2p[8][256];
  int tid = threadIdx.x;
  int b = blockIdx.y;
  int j0 = blockIdx.x * 256;
  a1l[tid] = a[tid]; a1l[256 + tid] = a[256 + tid];
  a2l[tid] = a[512 + tid]; a2l[256 + tid] = a[768 + tid];
  __syncthreads();
  int jv = (tid & 31) * 8;
  int nh = tid >> 5;
  const unsigned short* base = WhT + ((size_t)b * 512 + nh * 64) * 2048 + j0 + jv;
  float c1[8], c2[8];
#pragma unroll
  for (int e = 0; e < 8; ++e) { c1[e] = 0.f; c2[e] = 0.f; }
#pragma unroll 4
  for (int i = 0; i < 64; ++i) {
    u16x8 w = *(const u16x8*)(base + (size_t)i * 2048);
    float w1 = a1l[nh * 64 + i], w2 = a2l[nh * 64 + i];
#pragma unroll
    for (int e = 0; e < 8; ++e) {
      float wv = bf2f(w[e]);
      c1[e] += wv * w1;
      c2[e] += wv * w2;
    }
  }
#pragma unroll
  for (int e = 0; e < 8; ++e) { S1p[nh][jv + e] = c1[e]; S2p[nh][jv + e] = c2[e]; }
  __syncthreads();
  float v1 = 0.f, v2 = 0.f;
#pragma unroll
  for (int h = 0; h < 8; ++h) { v1 += S1p[h][tid]; v2 += S2p[h][tid]; }
  size_t o = (size_t)b * 2048 + j0 + tid;
  s1[o] = v1; s2[o] = v2;
  f1[o] = __expf(v2);
  f2[o] = __expf(0.1f * v2);
}

// ---------------- kernel 3: fused attention, 32-j half-tile double-buffered pipeline ----------------
__global__ __launch_bounds__(512, 2) void k_attn(const int* __restrict__ adj,
                                                 const unsigned short* __restrict__ WhT,
                                                 const float* __restrict__ s1g,
                                                 const float* __restrict__ s2g,
                                                 const float* __restrict__ f1g,
                                                 const float* __restrict__ f2g,
                                                 float* __restrict__ out) {
  __shared__ __align__(16) unsigned short Bl[2 * 512 * 32];   // 64KB, row 64B
  __shared__ __align__(16) unsigned short Pl[2 * 128 * 32];   // 16KB, row 64B
  __shared__ float f1l[2048], f2l[2048];                      // 16KB
  __shared__ float zl[128];
  __shared__ float red[8];
  int tid = threadIdx.x;
  int bx = blockIdx.x;
  int q = bx >> 3, xcd = bx & 7;
  int b = xcd * 2 + (q & 1);        // XCD k owns batches {2k,2k+1}: WhT (2x2MB) L2-resident
  int rb = q >> 1;
  int R0 = rb * 128;

  int lane = tid & 63, wid = tid >> 6;
  int wr2 = wid >> 2, wc = wid & 3;
  int r = tid >> 2, qc = tid & 3;

  const unsigned short* whbase = WhT + (size_t)b * 512 * 2048;
  const int* adjrow = adj + ((size_t)b * 2048 + R0 + r) * 2048 + qc * 8;

  auto stageB = [&](int j0h, int buf) {
#pragma unroll
    for (int pass = 0; pass < 4; ++pass) {
      int n = pass * 128 + (tid >> 2);
      int g = tid & 3;
      const unsigned short* src = whbase + (size_t)n * 2048 + j0h + ((g ^ (n & 3)) << 3);
      unsigned short* dst = Bl + buf * 16384 + pass * 4096 + wid * 512;
      GLD16(src, dst);
    }
  };

  // ---- early issue: B(tile0, half0) + adj tile0 ----
  stageB(0, 0);
  int4 aL0 = *(const int4*)(adjrow + 0);
  int4 aL1 = *(const int4*)(adjrow + 4);
  int4 aH0 = *(const int4*)(adjrow + 32);
  int4 aH1 = *(const int4*)(adjrow + 36);

  // ---- tables + gmax ----
  float lm = -1e30f;
#pragma unroll
  for (int i = 0; i < 4; ++i) {
    int idx = i * 512 + tid;
    float v = s2g[(size_t)b * 2048 + idx];
    f1l[idx] = f1g[(size_t)b * 2048 + idx];
    f2l[idx] = f2g[(size_t)b * 2048 + idx];
    lm = fmaxf(lm, v);
  }
#pragma unroll
  for (int s = 1; s < 64; s <<= 1) lm = fmaxf(lm, __shfl_xor(lm, s));
  if (lane == 0) red[wid] = lm;
  __syncthreads();
  float gmax = red[0];
#pragma unroll
  for (int i = 1; i < 8; ++i) gmax = fmaxf(gmax, red[i]);

  float s1r = s1g[(size_t)b * 2048 + R0 + r];
  float t0v = s1r + gmax;
  float M = (t0v > 0.f) ? t0v : 0.1f * t0v;   // lrelu upper bound -> softmax shift
  float E1 = __expf(s1r - M);
  float E2 = __expf(0.1f * s1r - M);
  float T1 = __expf(-s1r);                    // sign test: s1r+s2>0  <=>  f1>T1
  float zacc = 0.f;

  f32x4 acc[4][8];
#pragma unroll
  for (int i = 0; i < 4; ++i)
#pragma unroll
    for (int j = 0; j < 8; ++j) acc[i][j] = (f32x4){0.f, 0.f, 0.f, 0.f};

  auto computeP = [&](int j0h, int buf, int4 a0, int4 a1) {
    int av[8];
    av[0] = a0.x; av[1] = a0.y; av[2] = a0.z; av[3] = a0.w;
    av[4] = a1.x; av[5] = a1.y; av[6] = a1.z; av[7] = a1.w;
    int jb = j0h + qc * 8;
    float4 A1 = *(const float4*)(f1l + jb);
    float4 B1 = *(const float4*)(f1l + jb + 4);
    float4 A2 = *(const float4*)(f2l + jb);
    float4 B2 = *(const float4*)(f2l + jb + 4);
    float f1v[8] = {A1.x, A1.y, A1.z, A1.w, B1.x, B1.y, B1.z, B1.w};
    float f2v[8] = {A2.x, A2.y, A2.z, A2.w, B2.x, B2.y, B2.z, B2.w};
    u16x8 pk;
#pragma unroll
    for (int c = 0; c < 8; ++c) {
      bool pos = f1v[c] > T1;
      float Ev = pos ? E1 : E2;
      float Fv = pos ? f1v[c] : f2v[c];
      float p = (av[c] > 0) ? Ev * Fv : 0.f;
      unsigned short pb = f2bf(p);
      zacc += bf2f(pb);
      pk[c] = pb;
    }
    *(u16x8*)((char*)(Pl + buf * 4096) + r * 64 + ((qc ^ (r & 3)) << 4)) = pk;
  };

  auto mfmaPhase = [&](int buf) {
    const char* pb = (const char*)(Pl + buf * 4096);
    const char* bb = (const char*)(Bl + buf * 16384);
    int u = lane >> 4;
    short8 af[4];
#pragma unroll
    for (int mf = 0; mf < 4; ++mf) {
      int row = wr2 * 64 + mf * 16 + (lane & 15);
      af[mf] = *(const short8*)(pb + row * 64 + ((u ^ (row & 3)) << 4));
    }
#pragma unroll
    for (int nf = 0; nf < 8; ++nf) {
      int n = wc * 128 + nf * 16 + (lane & 15);
      short8 bv = *(const short8*)(bb + n * 64 + ((u ^ (n & 3)) << 4));
#pragma unroll
      for (int mf = 0; mf < 4; ++mf)
        acc[mf][nf] = __builtin_amdgcn_mfma_f32_16x16x32_bf16(af[mf], bv, acc[mf][nf], 0, 0, 0);
    }
  };

  __syncthreads();             // tables + Bl[0] ready
  computeP(0, 0, aL0, aL1);    // P for phase 0
  __syncthreads();             // Pl[0] ready

  int4 aHn0 = aH0, aHn1 = aH1, aLn0 = aL0, aLn1 = aL1;
  for (int t = 0; t < 32; ++t) {
    int j0 = t << 6;
    // even phase: compute buf0; prep (t,h1)->buf1; prefetch adj tile t+1
    if (t < 31) {
      aLn0 = *(const int4*)(adjrow + j0 + 64);
      aLn1 = *(const int4*)(adjrow + j0 + 68);
      aHn0 = *(const int4*)(adjrow + j0 + 96);
      aHn1 = *(const int4*)(adjrow + j0 + 100);
    }
    stageB(j0 + 32, 1);
    computeP(j0 + 32, 1, aH0, aH1);
    mfmaPhase(0);
    __syncthreads();
    // odd phase: compute buf1; prep (t+1,h0)->buf0
    if (t < 31) {
      stageB(j0 + 64, 0);
      computeP(j0 + 64, 0, aLn0, aLn1);
    }
    mfmaPhase(1);
    __syncthreads();
    aH0 = aHn0; aH1 = aHn1;
  }

  // ---- z reduction: 4 staging threads per row are adjacent lanes ----
  zacc += __shfl_xor(zacc, 1);
  zacc += __shfl_xor(zacc, 2);
  if (qc == 0) zl[r] = zacc;
  __syncthreads();

  // ---- epilogue: h' = elu(acc / z) ----
  float* obase;
  if (R0 < 1024) obase = out + ((size_t)b * 1024 + R0) * 512;
  else obase = out + (size_t)8388608 + ((size_t)b * 1024 + (R0 - 1024)) * 512;
#pragma unroll
  for (int mf = 0; mf < 4; ++mf) {
    int row0 = wr2 * 64 + mf * 16 + ((lane >> 4) << 2);
    float zi[4];
#pragma unroll
    for (int e = 0; e < 4; ++e) zi[e] = 1.f / zl[row0 + e];
#pragma unroll
    for (int nf = 0; nf < 8; ++nf) {
      int n = wc * 128 + nf * 16 + (lane & 15);
#pragma unroll
      for (int e = 0; e < 4; ++e) {
        float v = acc[mf][nf][e] * zi[e];
        v = (v > 0.f) ? v : (__expf(v) - 1.f);
        obase[(size_t)(row0 + e) * 512 + n] = v;
      }
    }
  }
}

extern "C" void kernel_launch(void* const* d_in, const int* in_sizes, int n_in,
                              void* d_out, int out_size, void* d_ws, size_t ws_size,
                              hipStream_t stream) {
  (void)in_sizes; (void)n_in; (void)out_size; (void)ws_size;
  const float* x_a = (const float*)d_in[0];
  const float* x_v = (const float*)d_in[1];
  const int*   adj = (const int*)d_in[2];
  const float* W   = (const float*)d_in[3];
  const float* a   = (const float*)d_in[4];
  float* out = (float*)d_out;

  char* ws = (char*)d_ws;
  unsigned short* WT  = (unsigned short*)ws;                       // 512 KB
  unsigned short* WhT = (unsigned short*)(ws + (1u << 19));        // 32 MB
  float* s1 = (float*)(ws + (1u << 19) + (1u << 25));              // 128 KB each
  float* s2 = s1 + 32768;
  float* f1 = s2 + 32768;
  float* f2 = f1 + 32768;

  hipLaunchKernelGGL(k_twp,  dim3(8, 8),   dim3(256), 0, stream, W, WT);
  hipLaunchKernelGGL(k_gemm, dim3(512),    dim3(256), 0, stream, x_a, x_v, WT, WhT);
  hipLaunchKernelGGL(k_s,    dim3(8, 16),  dim3(256), 0, stream, WhT, a, s1, s2, f1, f2);
  hipLaunchKernelGGL(k_attn, dim3(256),    dim3(512), 0, stream, adj, WhT, s1, s2, f1, f2, out);
}